// Round 1
// baseline (60.910 us; speedup 1.0000x reference)
//
#include <hip/hip_runtime.h>
#include <math.h>

// ANI featurization: B=4, N=23, out (B,N,1121) float32.
// One block per (b,i) atom row. 92 blocks x 256 threads.

namespace {
constexpr int B_  = 4;
constexpr int N_  = 23;
constexpr int RL_ = 32;
constexpr int AL_ = 8;
constexpr int NT_ = 5;                       // len(ATOM_CASES)
constexpr int NP_ = 15;                      // pairs (tj<=tk)
constexpr int L_  = AL_ * AL_;               // 64
constexpr int NCOL_ = 1 + NT_ * RL_ + NP_ * L_;  // 1121
constexpr float BOHR_F = 0.52917721092f;
}

__global__ __launch_bounds__(256)
void ani_feat_kernel(const float* __restrict__ coords,
                     const int* __restrict__ zs,
                     float* __restrict__ out)
{
    const int bi  = blockIdx.x;          // 0..B*N-1
    const int b   = bi / N_;
    const int i   = bi % N_;
    const int tid = threadIdx.x;

    __shared__ float s_dx[N_], s_dy[N_], s_dz[N_];
    __shared__ float s_d[N_], s_drc[N_], s_dac[N_];
    __shared__ int   s_t[N_];
    __shared__ int   s_npair;
    __shared__ float p_theta[N_ * N_];
    __shared__ float p_ravg [N_ * N_];
    __shared__ float p_w    [N_ * N_];
    __shared__ int   p_p    [N_ * N_];
    __shared__ float ang[4][NP_ * L_];   // one copy per wave

    // ---- Phase A: per-neighbor geometry ----
    if (tid < N_) {
        const int j = tid;
        const float cix = coords[(b * N_ + i) * 3 + 0] * BOHR_F;
        const float ciy = coords[(b * N_ + i) * 3 + 1] * BOHR_F;
        const float ciz = coords[(b * N_ + i) * 3 + 2] * BOHR_F;
        const float cjx = coords[(b * N_ + j) * 3 + 0] * BOHR_F;
        const float cjy = coords[(b * N_ + j) * 3 + 1] * BOHR_F;
        const float cjz = coords[(b * N_ + j) * 3 + 2] * BOHR_F;
        const float dx = cjx - cix, dy = cjy - ciy, dz = cjz - ciz;
        const float dd = sqrtf(dx * dx + dy * dy + dz * dz + 1e-7f);
        s_dx[j] = dx; s_dy[j] = dy; s_dz[j] = dz; s_d[j] = dd;
        float drc = 0.0f, dac = 0.0f;
        if (j != i) {   // (1 - eye) factor
            if (dd < 4.6f) drc = 0.5f * (cosf((float)M_PI * dd / 4.6f) + 1.0f);
            if (dd < 3.1f) dac = 0.5f * (cosf((float)M_PI * dd / 3.1f) + 1.0f);
        }
        s_drc[j] = drc; s_dac[j] = dac;
        const int z = zs[b * N_ + j];
        s_t[j] = (z == 1) ? 0 : (z == 6) ? 1 : (z == 7) ? 2 :
                 (z == 8) ? 3 : (z == 16) ? 4 : -1;
    }
    if (tid == 0) s_npair = 0;
    for (int idx = tid; idx < 4 * NP_ * L_; idx += 256)
        ((float*)ang)[idx] = 0.0f;
    __syncthreads();

    // ---- Phase B: radial features (threads 0..159 own (t,r)) ----
    if (tid < NT_ * RL_) {
        const int t = tid / RL_;
        const int r = tid % RL_;
        const float rs1   = (float)(4.6 / 31.0);         // Rs[1] in f32
        const float sq    = rs1 * rs1;                   // f32**2 like numpy
        const float ITA_R = (float)(3.0 / (double)sq);
        const float Rs_r  = (float)(4.6 * r / 31.0);
        float acc = 0.0f;
        #pragma unroll
        for (int j = 0; j < N_; ++j) {
            const float f = s_drc[j];
            if (s_t[j] == t && f > 0.0f) {
                const float df = s_d[j] - Rs_r;
                acc += expf(-ITA_R * df * df) * f;
            }
        }
        out[(size_t)(b * N_ + i) * NCOL_ + 1 + tid] = acc;
    }

    // ---- Phase C: build compact angular pair list ----
    for (int idx = tid; idx < N_ * N_; idx += 256) {
        const int j = idx / N_;
        const int k = idx % N_;
        const float wj = s_dac[j], wk = s_dac[k];
        const int tj = s_t[j], tk = s_t[k];
        if (wj > 0.0f && wk > 0.0f && tj >= 0 && tk >= 0 && tj <= tk) {
            const float vm    = s_dx[j] * s_dx[k] + s_dy[j] * s_dy[k] + s_dz[j] * s_dz[k];
            const float denom = s_d[j] * s_d[k] + 1e-5f;
            float ratio = vm / denom;
            ratio = fminf(1.0f, fmaxf(-1.0f, ratio));
            const int slot = atomicAdd(&s_npair, 1);
            p_theta[slot] = acosf(ratio);
            p_ravg [slot] = 0.5f * (s_d[j] + s_d[k]);
            p_w    [slot] = 2.0f * wj * wk;
            p_p    [slot] = tj * 5 - (tj * (tj - 1)) / 2 + (tk - tj);
        }
    }
    __syncthreads();

    // ---- Phase D: angular accumulation; 4 waves x 64 lanes (lane = l) ----
    {
        const int wave = tid >> 6;           // 0..3 (one wave each)
        const int l    = tid & 63;           // l = rs*8 + th_idx  (meshgrid order)
        const int rs_i = l >> 3;
        const int th_i = l & 7;
        const float Rs_l  = (float)(3.1 * rs_i / 7.0);
        const float th_l  = (float)(M_PI * th_i / 7.0);
        const float ITA_A = (float)(3.0 / ((3.1 / 7.0) * (3.1 / 7.0)));
        float* myang = ang[wave];
        const int np = s_npair;
        for (int s = wave; s < np; s += 4) {
            const float theta = p_theta[s];          // wave-uniform broadcast
            float a = 0.5f * (1.0f + cosf(theta - th_l));
            a = a * a; a = a * a; a = a * a;         // a^8
            a = a * a; a = a * a; a = a * a;         // a^64  (zeta = 64)
            const float dr = p_ravg[s] - Rs_l;
            const float e  = expf(-ITA_A * dr * dr);
            const float term = p_w[s] * a * e;
            myang[p_p[s] * L_ + l] += term;          // lane-owned column, no race
        }
    }
    __syncthreads();

    // ---- Phase E: reduce 4 copies + write angular block & z column ----
    const size_t row = (size_t)(b * N_ + i) * NCOL_;
    for (int idx = tid; idx < NP_ * L_; idx += 256) {
        const float v = ang[0][idx] + ang[1][idx] + ang[2][idx] + ang[3][idx];
        out[row + 1 + NT_ * RL_ + idx] = v;
    }
    if (tid == 0)
        out[row] = (float)zs[b * N_ + i];
}

extern "C" void kernel_launch(void* const* d_in, const int* in_sizes, int n_in,
                              void* d_out, int out_size, void* d_ws, size_t ws_size,
                              hipStream_t stream) {
    (void)in_sizes; (void)n_in; (void)d_ws; (void)ws_size; (void)out_size;
    const float* coords = (const float*)d_in[0];
    const int*   zs     = (const int*)d_in[1];
    float*       out    = (float*)d_out;
    ani_feat_kernel<<<B_ * N_, 256, 0, stream>>>(coords, zs, out);
}

// Round 2
// 59.602 us; speedup vs baseline: 1.0220x; 1.0220x over previous
//
#include <hip/hip_runtime.h>
#include <math.h>

// ANI featurization: B=4, N=23, out (B,N,1121) float32.
// One block per (b,i) atom row. 92 blocks x 256 threads.
// R1: removed acosf+cosf from angular path via cos(theta-t_l) =
//     cos_t*cos(t_l) + sin_t*sin(t_l); expf -> __expf.

namespace {
constexpr int B_  = 4;
constexpr int N_  = 23;
constexpr int RL_ = 32;
constexpr int AL_ = 8;
constexpr int NT_ = 5;                       // len(ATOM_CASES)
constexpr int NP_ = 15;                      // pairs (tj<=tk)
constexpr int L_  = AL_ * AL_;               // 64
constexpr int NCOL_ = 1 + NT_ * RL_ + NP_ * L_;  // 1121
constexpr float BOHR_F = 0.52917721092f;

// cos/sin of theta_l = l*pi/7, l=0..7 (np.linspace(0,pi,8))
__device__ __constant__ float COS_TH[8] = {
    1.0f, 0.90096886790241915f, 0.62348980185873360f, 0.22252093395631445f,
    -0.22252093395631440f, -0.62348980185873349f, -0.90096886790241915f, -1.0f };
__device__ __constant__ float SIN_TH[8] = {
    0.0f, 0.43388373911755812f, 0.78183148246802980f, 0.97492791218182362f,
    0.97492791218182362f, 0.78183148246802991f, 0.43388373911755823f, 0.0f };
}

__global__ __launch_bounds__(256)
void ani_feat_kernel(const float* __restrict__ coords,
                     const int* __restrict__ zs,
                     float* __restrict__ out)
{
    const int bi  = blockIdx.x;          // 0..B*N-1
    const int b   = bi / N_;
    const int i   = bi % N_;
    const int tid = threadIdx.x;

    __shared__ float s_dx[N_], s_dy[N_], s_dz[N_];
    __shared__ float s_d[N_], s_drc[N_], s_dac[N_];
    __shared__ int   s_t[N_];
    __shared__ int   s_npair;
    __shared__ float p_cs [N_ * N_];     // cos(theta)
    __shared__ float p_sn [N_ * N_];     // sin(theta)
    __shared__ float p_ravg[N_ * N_];
    __shared__ float p_w  [N_ * N_];
    __shared__ int   p_p  [N_ * N_];
    __shared__ float ang[4][NP_ * L_];   // one copy per wave

    // ---- Phase A: per-neighbor geometry ----
    if (tid < N_) {
        const int j = tid;
        const float cix = coords[(b * N_ + i) * 3 + 0] * BOHR_F;
        const float ciy = coords[(b * N_ + i) * 3 + 1] * BOHR_F;
        const float ciz = coords[(b * N_ + i) * 3 + 2] * BOHR_F;
        const float cjx = coords[(b * N_ + j) * 3 + 0] * BOHR_F;
        const float cjy = coords[(b * N_ + j) * 3 + 1] * BOHR_F;
        const float cjz = coords[(b * N_ + j) * 3 + 2] * BOHR_F;
        const float dx = cjx - cix, dy = cjy - ciy, dz = cjz - ciz;
        const float dd = sqrtf(dx * dx + dy * dy + dz * dz + 1e-7f);
        s_dx[j] = dx; s_dy[j] = dy; s_dz[j] = dz; s_d[j] = dd;
        float drc = 0.0f, dac = 0.0f;
        if (j != i) {   // (1 - eye) factor
            if (dd < 4.6f) drc = 0.5f * (__cosf((float)M_PI * dd / 4.6f) + 1.0f);
            if (dd < 3.1f) dac = 0.5f * (__cosf((float)M_PI * dd / 3.1f) + 1.0f);
        }
        s_drc[j] = drc; s_dac[j] = dac;
        const int z = zs[b * N_ + j];
        s_t[j] = (z == 1) ? 0 : (z == 6) ? 1 : (z == 7) ? 2 :
                 (z == 8) ? 3 : (z == 16) ? 4 : -1;
    }
    if (tid == 0) s_npair = 0;
    for (int idx = tid; idx < 4 * NP_ * L_; idx += 256)
        ((float*)ang)[idx] = 0.0f;
    __syncthreads();

    // ---- Phase B: radial features (threads 0..159 own (t,r)) ----
    if (tid < NT_ * RL_) {
        const int t = tid / RL_;
        const int r = tid % RL_;
        const float rs1   = (float)(4.6 / 31.0);         // Rs[1] in f32
        const float sq    = rs1 * rs1;
        const float ITA_R = (float)(3.0 / (double)sq);
        const float Rs_r  = (float)(4.6 * r / 31.0);
        float acc = 0.0f;
        #pragma unroll
        for (int j = 0; j < N_; ++j) {
            const float f = s_drc[j];
            if (s_t[j] == t && f > 0.0f) {
                const float df = s_d[j] - Rs_r;
                acc += __expf(-ITA_R * df * df) * f;
            }
        }
        out[(size_t)(b * N_ + i) * NCOL_ + 1 + tid] = acc;
    }

    // ---- Phase C: build compact angular pair list (no acos needed) ----
    for (int idx = tid; idx < N_ * N_; idx += 256) {
        const int j = idx / N_;
        const int k = idx % N_;
        const float wj = s_dac[j], wk = s_dac[k];
        const int tj = s_t[j], tk = s_t[k];
        if (wj > 0.0f && wk > 0.0f && tj >= 0 && tk >= 0 && tj <= tk) {
            const float vm    = s_dx[j] * s_dx[k] + s_dy[j] * s_dy[k] + s_dz[j] * s_dz[k];
            const float denom = s_d[j] * s_d[k] + 1e-5f;
            float cs = vm / denom;
            cs = fminf(1.0f, fmaxf(-1.0f, cs));
            const float sn = sqrtf(fmaxf(0.0f, 1.0f - cs * cs));  // sin(acos(cs)) >= 0
            const int slot = atomicAdd(&s_npair, 1);
            p_cs  [slot] = cs;
            p_sn  [slot] = sn;
            p_ravg[slot] = 0.5f * (s_d[j] + s_d[k]);
            p_w   [slot] = 2.0f * wj * wk;
            p_p   [slot] = tj * 5 - (tj * (tj - 1)) / 2 + (tk - tj);
        }
    }
    __syncthreads();

    // ---- Phase D: angular accumulation; 4 waves x 64 lanes (lane = l) ----
    {
        const int wave = tid >> 6;           // 0..3 (one wave each)
        const int l    = tid & 63;           // l = rs*8 + th_idx  (meshgrid order)
        const int rs_i = l >> 3;
        const int th_i = l & 7;
        const float Rs_l  = (float)(3.1 * rs_i / 7.0);
        const float ITA_A = (float)(3.0 / ((3.1 / 7.0) * (3.1 / 7.0)));
        const float c_l = COS_TH[th_i];
        const float s_l = SIN_TH[th_i];
        float* myang = ang[wave];
        const int np = s_npair;
        for (int s = wave; s < np; s += 4) {
            const float cs = p_cs[s];                // wave-uniform broadcasts
            const float sn = p_sn[s];
            // cos(theta - th_l) = cs*c_l + sn*s_l  (theta in [0,pi])
            float a = 0.5f * (1.0f + cs * c_l + sn * s_l);
            a = a * a; a = a * a; a = a * a;         // a^8
            a = a * a; a = a * a; a = a * a;         // a^64  (zeta = 64)
            const float dr = p_ravg[s] - Rs_l;
            const float e  = __expf(-ITA_A * dr * dr);
            const float term = p_w[s] * a * e;
            myang[p_p[s] * L_ + l] += term;          // lane-owned column, no race
        }
    }
    __syncthreads();

    // ---- Phase E: reduce 4 copies + write angular block & z column ----
    const size_t row = (size_t)(b * N_ + i) * NCOL_;
    for (int idx = tid; idx < NP_ * L_; idx += 256) {
        const float v = ang[0][idx] + ang[1][idx] + ang[2][idx] + ang[3][idx];
        out[row + 1 + NT_ * RL_ + idx] = v;
    }
    if (tid == 0)
        out[row] = (float)zs[b * N_ + i];
}

extern "C" void kernel_launch(void* const* d_in, const int* in_sizes, int n_in,
                              void* d_out, int out_size, void* d_ws, size_t ws_size,
                              hipStream_t stream) {
    (void)in_sizes; (void)n_in; (void)d_ws; (void)ws_size; (void)out_size;
    const float* coords = (const float*)d_in[0];
    const int*   zs     = (const int*)d_in[1];
    float*       out    = (float*)d_out;
    ani_feat_kernel<<<B_ * N_, 256, 0, stream>>>(coords, zs, out);
}